// Round 10
// baseline (663.705 us; speedup 1.0000x reference)
//
#include <hip/hip_runtime.h>
#include <hip/hip_bf16.h>
#include <stdint.h>

typedef __bf16 bf16;
typedef signed char i8;
typedef __bf16 v8bf __attribute__((ext_vector_type(8)));
typedef __bf16 v4bf __attribute__((ext_vector_type(4)));
typedef signed char v8i8 __attribute__((ext_vector_type(8)));
typedef int    v4i  __attribute__((ext_vector_type(4)));
typedef float  f32x16 __attribute__((ext_vector_type(16)));

#define MFMA32(a,b,c)   __builtin_amdgcn_mfma_f32_32x32x16_bf16((a),(b),(c),0,0,0)
#define MFMA_I8(a,b,c)  __builtin_amdgcn_mfma_i32_16x16x64_i8((a),(b),(c),0,0,0)

#define INV_D2 (1.0f / 4194304.0f)
#define INV_KV (1.0f / 1048576.0f)
#define INV_F  (1.0f / 16777216.0f)

__device__ __forceinline__ void glds16(const void* g, void* l) {
  __builtin_amdgcn_global_load_lds(
      (const __attribute__((address_space(1))) void*)g,
      (__attribute__((address_space(3))) void*)l, 16, 0, 0);
}

__device__ __forceinline__ float wred_sum(float v) {
#pragma unroll
  for (int o = 32; o; o >>= 1) v += __shfl_xor(v, o);
  return v;
}
__device__ __forceinline__ float wred_max(float v) {
#pragma unroll
  for (int o = 32; o; o >>= 1) v = fmaxf(v, __shfl_xor(v, o));
  return v;
}

__device__ __forceinline__ unsigned int packbf(float a, float b) {
  union { bf16 h[2]; unsigned int u; } x;
  x.h[0] = (bf16)a; x.h[1] = (bf16)b;
  return x.u;
}

// ---------------- dtype sniffer (inputs turned out fp32; keep robust) ----------------
__global__ void k_sniff(const unsigned short* __restrict__ x, int* __restrict__ flag) {
  int cnt = 0;
  for (int i = threadIdx.x; i < 2048; i += 64) {
    const unsigned short u = x[i];
    const int e = (u >> 7) & 0xFF;
    if (u == 0 || (e >= 100 && e <= 140)) cnt++;
  }
#pragma unroll
  for (int o = 32; o; o >>= 1) cnt += __shfl_xor(cnt, o);
  if (threadIdx.x == 0) flag[0] = (cnt >= 1844) ? 0 : 1;  // 0 = bf16, 1 = f32
}

// ---------------- small utility kernels ----------------

__global__ void k_zero(float* p, int n) {
  int i = threadIdx.x;
  if (i < n) p[i] = 0.0f;
}

// zero a float4-aligned buffer; grid = bytes/16/256
__global__ __launch_bounds__(256) void k_zerof(float4* __restrict__ p) {
  p[(size_t)blockIdx.x * 256 + threadIdx.x] = make_float4(0.f, 0.f, 0.f, 0.f);
}

// fused abs-sum over all 6 weights; segments in 64K-element units:
// wq 64 | wk 16 | wv 16 | wo 64 | w1 256 | w2 256  => grid = 672 blocks
__global__ __launch_bounds__(256) void k_abssum6(const void* __restrict__ p0, const void* __restrict__ p1,
                                                 const void* __restrict__ p2, const void* __restrict__ p3,
                                                 const void* __restrict__ p4, const void* __restrict__ p5,
                                                 const int* __restrict__ flag, float* __restrict__ out) {
  const int b = blockIdx.x, tid = threadIdx.x;
  const void* w; int seg, base;
  if (b < 64)       { w = p0; seg = 0; base = b; }
  else if (b < 80)  { w = p1; seg = 1; base = b - 64; }
  else if (b < 96)  { w = p2; seg = 2; base = b - 80; }
  else if (b < 160) { w = p3; seg = 3; base = b - 96; }
  else if (b < 416) { w = p4; seg = 4; base = b - 160; }
  else              { w = p5; seg = 5; base = b - 416; }
  const int f32 = flag[0];
  __shared__ float sred[4];
  float s = 0.0f;
  if (f32) {
    const float4* p = (const float4*)w + (size_t)base * 16384;
#pragma unroll 4
    for (int i = 0; i < 64; i++) {
      float4 a = p[i * 256 + tid];
      s += fabsf(a.x) + fabsf(a.y) + fabsf(a.z) + fabsf(a.w);
    }
  } else {
    const v8bf* p = (const v8bf*)w + (size_t)base * 8192;
#pragma unroll 4
    for (int i = 0; i < 32; i++) {
      v8bf v = p[i * 256 + tid];
#pragma unroll
      for (int j = 0; j < 8; j++) s += fabsf((float)v[j]);
    }
  }
  s = wred_sum(s);
  if ((tid & 63) == 0) sred[tid >> 6] = s;
  __syncthreads();
  if (tid == 0) atomicAdd(out + seg, sred[0] + sred[1] + sred[2] + sred[3]);
}

// fused ternary weight quant -> int8 for all 6 weights; 2048 elems/block:
// wq 2048 | wk 512 | wv 512 | wo 2048 | w1 8192 | w2 8192 => grid = 21504
__global__ __launch_bounds__(256) void k_wquant6(const void* __restrict__ p0, const void* __restrict__ p1,
                                                 const void* __restrict__ p2, const void* __restrict__ p3,
                                                 const void* __restrict__ p4, const void* __restrict__ p5,
                                                 i8* __restrict__ d0, i8* __restrict__ d1,
                                                 i8* __restrict__ d2, i8* __restrict__ d3,
                                                 i8* __restrict__ d4, i8* __restrict__ d5,
                                                 const float* __restrict__ wsum,
                                                 const int* __restrict__ flag) {
  const int b = blockIdx.x;
  const void* w; i8* o; int seg, base; float invn;
  if (b < 2048)       { w = p0; o = d0; seg = 0; base = b;         invn = INV_D2; }
  else if (b < 2560)  { w = p1; o = d1; seg = 1; base = b - 2048;  invn = INV_KV; }
  else if (b < 3072)  { w = p2; o = d2; seg = 2; base = b - 2560;  invn = INV_KV; }
  else if (b < 5120)  { w = p3; o = d3; seg = 3; base = b - 3072;  invn = INV_D2; }
  else if (b < 13312) { w = p4; o = d4; seg = 4; base = b - 5120;  invn = INV_F; }
  else                { w = p5; o = d5; seg = 5; base = b - 13312; invn = INV_F; }
  const int gid = base * 256 + threadIdx.x;
  const int i = gid * 8;
  const float ws = 1.0f / fmaxf(wsum[seg] * invn, 1e-5f);
  const int f32 = flag[0];
  float v[8];
  if (f32) {
    float4 a = ((const float4*)w)[gid * 2];
    float4 b4 = ((const float4*)w)[gid * 2 + 1];
    v[0] = a.x; v[1] = a.y; v[2] = a.z; v[3] = a.w;
    v[4] = b4.x; v[5] = b4.y; v[6] = b4.z; v[7] = b4.w;
  } else {
    v8bf t = *(const v8bf*)((const bf16*)w + i);
#pragma unroll
    for (int j = 0; j < 8; j++) v[j] = (float)t[j];
  }
  v8i8 r;
#pragma unroll
  for (int j = 0; j < 8; j++) {
    float t = rintf(v[j] * ws);
    r[j] = (i8)fminf(fmaxf(t, -1.0f), 1.0f);
  }
  *(v8i8*)(o + i) = r;
}

// LayerNorm + per-row absmax quantize -> int8.
template <bool XINT>
__global__ __launch_bounds__(256) void k_lnq(const void* __restrict__ x, const void* __restrict__ g,
                                             const void* __restrict__ b, i8* __restrict__ q,
                                             float* __restrict__ sc, const int* __restrict__ flag) {
  const int row = blockIdx.x, tid = threadIdx.x;
  const int f32 = flag[0];
  __shared__ float sred[4];
  float v[8];
#pragma unroll
  for (int i = 0; i < 8; i++) {
    const size_t idx = (size_t)row * 2048 + tid + 256 * i;
    if (XINT)      v[i] = ((const float*)x)[idx];
    else if (f32)  v[i] = ((const float*)x)[idx];
    else           v[i] = (float)((const bf16*)x)[idx];
  }
  float s = 0.0f;
#pragma unroll
  for (int i = 0; i < 8; i++) s += v[i];
  s = wred_sum(s);
  if ((tid & 63) == 0) sred[tid >> 6] = s;
  __syncthreads();
  const float mean = (sred[0] + sred[1] + sred[2] + sred[3]) * (1.0f / 2048.0f);
  __syncthreads();
  float vs = 0.0f;
#pragma unroll
  for (int i = 0; i < 8; i++) { float d = v[i] - mean; vs += d * d; }
  vs = wred_sum(vs);
  if ((tid & 63) == 0) sred[tid >> 6] = vs;
  __syncthreads();
  const float rstd = rsqrtf((sred[0] + sred[1] + sred[2] + sred[3]) * (1.0f / 2048.0f) + 1e-6f);
  __syncthreads();
  float hq[8];
  float am = 0.0f;
#pragma unroll
  for (int i = 0; i < 8; i++) {
    const int c = tid + 256 * i;
    const float gv = f32 ? ((const float*)g)[c] : (float)((const bf16*)g)[c];
    const float bv = f32 ? ((const float*)b)[c] : (float)((const bf16*)b)[c];
    hq[i] = (v[i] - mean) * rstd * gv + bv;
    am = fmaxf(am, fabsf(hq[i]));
  }
  am = wred_max(am);
  if ((tid & 63) == 0) sred[tid >> 6] = am;
  __syncthreads();
  am = fmaxf(fmaxf(sred[0], sred[1]), fmaxf(sred[2], sred[3]));
  const float cl = fmaxf(am, 1e-5f);
  const float s127 = 127.0f / cl;
#pragma unroll
  for (int i = 0; i < 8; i++) {
    float r = rintf(hq[i] * s127);
    r = fminf(fmaxf(r, -128.0f), 127.0f);
    q[(size_t)row * 2048 + tid + 256 * i] = (i8)r;
  }
  if (tid == 0) sc[row] = cl * (1.0f / 127.0f);
}

// plain per-row absmax quantize bf16 -> int8
template <int IT>
__global__ __launch_bounds__(256) void k_rowq(const bf16* __restrict__ in, i8* __restrict__ q,
                                              float* __restrict__ sc) {
  const int row = blockIdx.x, tid = threadIdx.x;
  const int C = IT * 256;
  __shared__ float sred[4];
  const bf16* xr = in + (size_t)row * C;
  float v[IT];
  float am = 0.0f;
#pragma unroll
  for (int i = 0; i < IT; i++) {
    v[i] = (float)xr[tid + 256 * i];
    am = fmaxf(am, fabsf(v[i]));
  }
  am = wred_max(am);
  if ((tid & 63) == 0) sred[tid >> 6] = am;
  __syncthreads();
  am = fmaxf(fmaxf(sred[0], sred[1]), fmaxf(sred[2], sred[3]));
  const float cl = fmaxf(am, 1e-5f);
  const float s127 = 127.0f / cl;
#pragma unroll
  for (int i = 0; i < IT; i++) {
    float r = rintf(v[i] * s127);
    r = fminf(fmaxf(r, -128.0f), 127.0f);
    q[(size_t)row * C + tid + 256 * i] = (i8)r;
  }
  if (tid == 0) sc[row] = cl * (1.0f / 127.0f);
}

// ---------------- int8 GEMM: 2-deep counted-vmcnt pipeline (T3/T4), raw barriers ----------------
// Per K-step: compute(buf[t&1]) ; bar(readers done) ; issue t+2 into buf[t&1] ;
// s_waitcnt vmcnt(4) -> tile t+1's 4 loads landed (t+2's stay IN FLIGHT across the
// barrier) ; bar. Raw s_barrier does NOT drain vmcnt (m201 pattern) -- this removes
// the __syncthreads-mandated vmcnt(0) drain that stalled every K-step (~300cyc).
// sched_barrier(0) after each barrier pins next-iteration ds_reads below their guard.
// Barrier counts are uniform across waves (gated only on uniform t/nst) -> no deadlock.
// EPI 2: out bf16 = relu(sA[m]*cw*val)^2   (w1 -> F; direct, no split)
// EPI 4: atomicAdd i32 partial into out    (split-K; exact integer)
template <int EPI>
__global__ __launch_bounds__(256) void k_gemm(const i8* __restrict__ A, const i8* __restrict__ B,
                                              const float* __restrict__ sA,
                                              const float* __restrict__ wsum, float winv,
                                              void* __restrict__ out,
                                              int M, int N, int K, int Kc,
                                              const int* __restrict__ flag) {
  __shared__ __align__(16) i8 As[2][128 * 64];
  __shared__ __align__(16) i8 Bs[2][128 * 64];
  const int tid = threadIdx.x;
  const int lane = tid & 63;
  const int ml = lane & 15;
  const int q4 = lane >> 4;
  const int wid = tid >> 6;
  const int wM = wid >> 1;
  const int wN = wid & 1;
  const int m0 = blockIdx.y * 128;
  const int n0 = blockIdx.x * 128;

  const int r0 = tid >> 2;           // 0..63
  const int c0 = (tid & 3) * 16;     // 0,16,32,48
  const i8* Ag0 = A + (size_t)(m0 + r0) * K + c0;
  const i8* Ag1 = Ag0 + (size_t)64 * K;
  const i8* Bg0 = B + (size_t)(n0 + r0) * K + c0;
  const i8* Bg1 = Bg0 + (size_t)64 * K;
  const int l0 = wid * 1024;         // lane l of wave w -> wavebase + l*16B
  const int l1 = 4096 + wid * 1024;

  const int kbeg = blockIdx.z * Kc;
  const int nst = Kc >> 6;

  auto issue = [&](int tt) {
    const int k0 = kbeg + (tt << 6);
    const int bb = tt & 1;
    glds16(Ag0 + k0, &As[bb][l0]);
    glds16(Ag1 + k0, &As[bb][l1]);
    glds16(Bg0 + k0, &Bs[bb][l0]);
    glds16(Bg1 + k0, &Bs[bb][l1]);
  };

  // prologue: prime 2 tiles, wait tile 0 (tile 1 stays in flight)
  issue(0);
  if (nst > 1) {
    issue(1);
    asm volatile("s_waitcnt vmcnt(4)" ::: "memory");
  } else {
    asm volatile("s_waitcnt vmcnt(0)" ::: "memory");
  }
  __builtin_amdgcn_s_barrier();
  __builtin_amdgcn_sched_barrier(0);

  v4i acc[4][4] = {};

  for (int t = 0; t < nst; ++t) {
    const int cb = t & 1;
    v4i af[4], bfr[4];
#pragma unroll
    for (int i = 0; i < 4; i++) af[i] = *(const v4i*)&As[cb][(wM * 64 + i * 16 + ml) * 64 + q4 * 16];
#pragma unroll
    for (int j = 0; j < 4; j++) bfr[j] = *(const v4i*)&Bs[cb][(wN * 64 + j * 16 + ml) * 64 + q4 * 16];
#pragma unroll
    for (int i = 0; i < 4; i++)
#pragma unroll
      for (int j = 0; j < 4; j++) acc[i][j] = MFMA_I8(af[i], bfr[j], acc[i][j]);
    __builtin_amdgcn_sched_barrier(0);
    __builtin_amdgcn_s_barrier();          // all waves done reading buf[cb]
    __builtin_amdgcn_sched_barrier(0);
    if (t + 2 < nst) {
      issue(t + 2);                        // overwrite buf[cb]
      asm volatile("s_waitcnt vmcnt(4)" ::: "memory");  // tile t+1 landed; t+2 in flight
      __builtin_amdgcn_s_barrier();
      __builtin_amdgcn_sched_barrier(0);
    } else if (t + 1 < nst) {
      asm volatile("s_waitcnt vmcnt(0)" ::: "memory");  // only tile t+1 outstanding
      __builtin_amdgcn_s_barrier();
      __builtin_amdgcn_sched_barrier(0);
    }
  }

  if (EPI == 4) {
    int* ob = (int*)out;
#pragma unroll
    for (int i = 0; i < 4; i++)
#pragma unroll
      for (int r = 0; r < 4; r++) {
        const int row = m0 + wM * 64 + i * 16 + q4 * 4 + r;
#pragma unroll
        for (int j = 0; j < 4; j++) {
          const int col = n0 + wN * 64 + j * 16 + ml;
          atomicAdd(ob + (size_t)row * N + col, acc[i][j][r]);
        }
      }
    return;
  }

  // EPI == 2 (direct relu^2 bf16)
  const float cw = fmaxf(wsum[0] * winv, 1e-5f);
#pragma unroll
  for (int i = 0; i < 4; i++) {
#pragma unroll
    for (int r = 0; r < 4; r++) {
      const int row = m0 + wM * 64 + i * 16 + q4 * 4 + r;
      const float sa = sA[row] * cw;
#pragma unroll
      for (int j = 0; j < 4; j++) {
        const int col = n0 + wN * 64 + j * 16 + ml;
        const float val = (float)acc[i][j][r] * sa;
        float u = fmaxf(val, 0.0f);
        ((bf16*)out)[(size_t)row * N + col] = (bf16)(u * u);
      }
    }
  }
}

// ---------------- split-K scale/residual epilogues (i32 acc in) ----------------
// MODE 2: out flag-typed = x1(f32) + acc*sA[row]*cw     (final)
template <int MODE>
__global__ __launch_bounds__(256) void k_epi(const int* __restrict__ acc, int lda, int cofs,
                                             int ncols,
                                             const float* __restrict__ sA,
                                             const float* __restrict__ wsum, float winv,
                                             const void* __restrict__ resid,
                                             void* __restrict__ out,
                                             const int* __restrict__ flag) {
  const int row = blockIdx.x, tid = threadIdx.x;
  const float cw = fmaxf(wsum[0] * winv, 1e-5f);
  const float srow = sA[row] * cw;
  const int f32 = flag[0];
  for (int c = tid * 4; c < ncols; c += 1024) {
    const v4i a = *(const v4i*)(acc + (size_t)row * lda + cofs + c);
    const float v0 = (float)a[0] * srow, v1 = (float)a[1] * srow;
    const float v2 = (float)a[2] * srow, v3 = (float)a[3] * srow;
    const size_t o = (size_t)row * ncols + c;
    const float4 rv = *(const float4*)((const float*)resid + o);
    const float o0 = rv.x + v0, o1 = rv.y + v1, o2 = rv.z + v2, o3 = rv.w + v3;
    if (f32) {
      *(float4*)((float*)out + o) = make_float4(o0, o1, o2, o3);
    } else {
      v4bf r;
      r[0] = (bf16)o0; r[1] = (bf16)o1; r[2] = (bf16)o2; r[3] = (bf16)o3;
      *(v4bf*)((bf16*)out + o) = r;
    }
  }
}

// fused wo-epilogue + LayerNorm + quant: x1 = x + acc*so[row]*cw (write f32),
// then LN(g2,b2) + row absmax quant -> xq2, s2. Replaces k_epi<1> + k_lnq<true>
// (saves the 16MB x1 re-read; math bitwise-identical to the two-kernel path).
__global__ __launch_bounds__(256) void k_epi1ln(const int* __restrict__ acc,
                                                const float* __restrict__ so_,
                                                const float* __restrict__ wsum,
                                                const void* __restrict__ xres,
                                                float* __restrict__ x1,
                                                const void* __restrict__ g, const void* __restrict__ b,
                                                i8* __restrict__ q, float* __restrict__ sc,
                                                const int* __restrict__ flag) {
  const int row = blockIdx.x, tid = threadIdx.x;
  const int f32 = flag[0];
  __shared__ float sred[4];
  const float srow = so_[row] * fmaxf(wsum[3] * INV_D2, 1e-5f);
  float v[8];
#pragma unroll
  for (int i = 0; i < 8; i++) {
    const size_t idx = (size_t)row * 2048 + tid + 256 * i;
    const float a = (float)acc[idx] * srow;
    const float rv = f32 ? ((const float*)xres)[idx] : (float)((const bf16*)xres)[idx];
    v[i] = rv + a;
    x1[idx] = v[i];
  }
  float s = 0.0f;
#pragma unroll
  for (int i = 0; i < 8; i++) s += v[i];
  s = wred_sum(s);
  if ((tid & 63) == 0) sred[tid >> 6] = s;
  __syncthreads();
  const float mean = (sred[0] + sred[1] + sred[2] + sred[3]) * (1.0f / 2048.0f);
  __syncthreads();
  float vs = 0.0f;
#pragma unroll
  for (int i = 0; i < 8; i++) { float d = v[i] - mean; vs += d * d; }
  vs = wred_sum(vs);
  if ((tid & 63) == 0) sred[tid >> 6] = vs;
  __syncthreads();
  const float rstd = rsqrtf((sred[0] + sred[1] + sred[2] + sred[3]) * (1.0f / 2048.0f) + 1e-6f);
  __syncthreads();
  float hq[8];
  float am = 0.0f;
#pragma unroll
  for (int i = 0; i < 8; i++) {
    const int c = tid + 256 * i;
    const float gv = f32 ? ((const float*)g)[c] : (float)((const bf16*)g)[c];
    const float bv = f32 ? ((const float*)b)[c] : (float)((const bf16*)b)[c];
    hq[i] = (v[i] - mean) * rstd * gv + bv;
    am = fmaxf(am, fabsf(hq[i]));
  }
  am = wred_max(am);
  if ((tid & 63) == 0) sred[tid >> 6] = am;
  __syncthreads();
  am = fmaxf(fmaxf(sred[0], sred[1]), fmaxf(sred[2], sred[3]));
  const float cl = fmaxf(am, 1e-5f);
  const float s127 = 127.0f / cl;
#pragma unroll
  for (int i = 0; i < 8; i++) {
    float r = rintf(hq[i] * s127);
    r = fminf(fmaxf(r, -128.0f), 127.0f);
    q[(size_t)row * 2048 + tid + 256 * i] = (i8)r;
  }
  if (tid == 0) sc[row] = cl * (1.0f / 127.0f);
}

// fused Q+K epilogue. Q: plain [t][2048]. K: head-major tiled PRE-SWIZZLED layout
// Kh[kvh][t][64]: elem = kvh*131072 + (t>>5)*2048 + (t&31)*64 + (((d>>3)^(t&7))<<3) + (d&7)
__global__ __launch_bounds__(256) void k_epiQK(const int* __restrict__ acc,
                                               const float* __restrict__ sA,
                                               const float* __restrict__ wsum,
                                               bf16* __restrict__ Qb, bf16* __restrict__ Kh) {
  const int row = blockIdx.x, tid = threadIdx.x;  // row = token t
  const float cw0 = fmaxf(wsum[0] * INV_D2, 1e-5f);
  const float cw1 = fmaxf(wsum[1] * INV_KV, 1e-5f);
  const float sa = sA[row];
  bf16* kb_ = Kh + ((size_t)(row >> 5) * 2048) + (row & 31) * 64;
  const int rx = row & 7;
  for (int c = tid * 4; c < 2560; c += 1024) {
    const v4i a = *(const v4i*)(acc + (size_t)row * 2560 + c);
    if (c < 2048) {
      v4bf r;
#pragma unroll
      for (int j = 0; j < 4; j++) r[j] = (bf16)((float)a[j] * sa * cw0);
      *(v4bf*)(Qb + (size_t)row * 2048 + c) = r;
    } else {
      const int j0 = c - 2048;
      const int kvh = j0 >> 6, d = j0 & 63;
      v4bf r;
#pragma unroll
      for (int j = 0; j < 4; j++) r[j] = (bf16)((float)a[j] * sa * cw1);
      const int elem = ((((d >> 3) ^ rx) << 3) + (d & 7));
      *(v4bf*)(kb_ + (size_t)kvh * 131072 + elem) = r;
    }
  }
}

// Vt epilogue -> head-major tile-blocked PRE-SWIZZLED V^T:
// Vtb[kvh][tile][64 d][32 t]: elem = kvh*131072 + (t>>5)*2048 + d*32
//                                   + (((t&31)>>3 ^ ((d>>1)&3))<<3) + (t&7)
__global__ __launch_bounds__(256) void k_epiVt(const int* __restrict__ acc,
                                               const float* __restrict__ sT,
                                               const float* __restrict__ wsum,
                                               bf16* __restrict__ Vtb) {
  const int vr = blockIdx.x, tid = threadIdx.x;  // vr = 0..511 (kvh*64 + d)
  const int kvh = vr >> 6, dd = vr & 63;
  const float cw = fmaxf(wsum[2] * INV_KV, 1e-5f);
  const int sw = (dd >> 1) & 3;
  bf16* vb = Vtb + (size_t)kvh * 131072 + dd * 32;
  for (int c = tid * 4; c < 2048; c += 1024) {
    const v4i a = *(const v4i*)(acc + (size_t)vr * 2048 + c);
    const float4 sc = *(const float4*)(sT + c);
    v4bf r;
    r[0] = (bf16)((float)a[0] * sc.x * cw);
    r[1] = (bf16)((float)a[1] * sc.y * cw);
    r[2] = (bf16)((float)a[2] * sc.z * cw);
    r[3] = (bf16)((float)a[3] * sc.w * cw);
    const int tq = c & 31;
    const int elem = (c >> 5) * 2048 + ((((tq >> 3) ^ sw) << 3) + (tq & 7));
    *(v4bf*)(vb + elem) = r;
  }
}

// ---------------- MFMA flash attention (causal, GQA 32q/8kv heads, D=64) ----------------
// r8 form (90.5us): swapped-operand 32x32, in-register softmax, coalesced LDS
// staging from pre-swizzled head-major K/V, double-buffered. Parked at plateau.
__global__ __launch_bounds__(64) void k_attn(const bf16* __restrict__ Q, const bf16* __restrict__ Kh,
                                             const bf16* __restrict__ Vtb, bf16* __restrict__ O) {
  __shared__ __align__(16) bf16 Kl[2][2048];
  __shared__ __align__(16) bf16 Vl[2][2048];
  const int h = blockIdx.y;
  const int kvh = h >> 2;
  const int t = (blockIdx.x + ((h >> 2) << 3)) & 63;  // balanced q-tile swizzle
  const int qw0 = t * 32;
  const int lane = threadIdx.x;
  const int ql = lane & 31;
  const int hi = lane >> 5;

  v8bf qf[4];
  {
    const bf16* qp = Q + (size_t)(qw0 + ql) * 2048 + h * 64 + hi * 8;
#pragma unroll
    for (int c = 0; c < 4; c++) qf[c] = *(const v8bf*)(qp + c * 16);
  }

  float m = -1e30f, l = 0.0f;
  f32x16 acc0 = {}, acc1 = {};

  const bf16* khead = Kh + (size_t)kvh * 131072 + lane * 8;
  const bf16* vhead = Vtb + (size_t)kvh * 131072 + lane * 8;

#pragma unroll
  for (int cc = 0; cc < 4; cc++) {
    glds16(khead + cc * 512, &Kl[0][cc * 512]);
    glds16(vhead + cc * 512, &Vl[0][cc * 512]);
  }
  asm volatile("s_waitcnt vmcnt(0)" ::: "memory");
  int cb = 0;

  for (int kb = 0; kb <= qw0; kb += 32) {
    if (kb + 32 <= qw0) {
      const int tb = ((kb + 32) >> 5) * 2048;
#pragma unroll
      for (int cc = 0; cc < 4; cc++) {
        glds16(khead + tb + cc * 512, &Kl[cb ^ 1][cc * 512]);
        glds16(vhead + tb + cc * 512, &Vl[cb ^ 1][cc * 512]);
      }
    }
    f32x16 s = {};
    {
      const char* kl = (const char*)&Kl[cb][0] + ql * 128;
#pragma unroll
      for (int c = 0; c < 4; c++) {
        const int sl = ((2 * c + hi) ^ (ql & 7)) << 4;
        const v8bf kf = *(const v8bf*)(kl + sl);
        s = MFMA32(kf, qf[c], s);
      }
    }
    const bool diag = (kb == qw0);
    float p[16];
    float rm = -1e30f;
#pragma unroll
    for (int r = 0; r < 16; r++) {
      float v = s[r] * 0.125f;
      const int koff = (r & 3) + ((r >> 2) << 3) + (hi << 2);
      if (diag && koff > ql) v = -1e30f;
      p[r] = v;
      rm = fmaxf(rm, v);
    }
    rm = fmaxf(rm, __shfl_xor(rm, 32));
    const float mn = fmaxf(m, rm);
    const float alpha = __expf(m - mn);
    m = mn;
    float rs = 0.0f;
#pragma unroll
    for (int r = 0; r < 16; r++) {
      p[r] = __expf(p[r] - mn);
      rs += p[r];
    }
    rs += __shfl_xor(rs, 32);
    l = l * alpha + rs;
#pragma unroll
    for (int r = 0; r < 16; r++) { acc0[r] *= alpha; acc1[r] *= alpha; }

    unsigned int w0 = packbf(p[0], p[1]),   w2 = packbf(p[4], p[5]);
    unsigned int w1 = packbf(p[2], p[3]),   w3 = packbf(p[6], p[7]);
    unsigned int x0 = packbf(p[8], p[9]),   x2 = packbf(p[12], p[13]);
    unsigned int x1 = packbf(p[10], p[11]), x3 = packbf(p[14], p[15]);
    asm("v_permlane32_swap_b32 %0, %1" : "+v"(w0), "+v"(w2));
    asm("v_permlane32_swap_b32 %0, %1" : "+v"(w1), "+v"(w3));
    asm("v_permlane32_swap_b32 %0, %1" : "+v"(x0), "+v"(x2));
    asm("v_permlane32_swap_b32 %0, %1" : "+v"(x1), "+v"(x3));
    union BU { unsigned int u[4]; v8bf v; } B0, B1;
    B0.u[0] = w0; B0.u[1] = w1; B0.u[2] = w2; B0.u[3] = w3;
    B1.u[0] = x0; B1.u[1] = x1; B1.u[2] = x2; B1.u[3] = x3;

    {
      const char* vl = (const char*)&Vl[cb][0] + ql * 64;
      const int sx = (ql >> 1) & 3;
      const int sl0 = ((0 + hi) ^ sx) << 4;
      const int sl1 = ((2 + hi) ^ sx) << 4;
      const v8bf v00 = *(const v8bf*)(vl + sl0);
      const v8bf v01 = *(const v8bf*)(vl + sl1);
      const v8bf v10 = *(const v8bf*)(vl + 2048 + sl0);
      const v8bf v11 = *(const v8bf*)(vl + 2048 + sl1);
      acc0 = MFMA32(v00, B0.v, acc0);
      acc0 = MFMA32(v01, B1.v, acc0);
      acc1 = MFMA32(v10, B0.v, acc1);
      acc1 = MFMA32(v11, B1.v, acc1);
    }
    asm volatile("s_waitcnt vmcnt(0)" ::: "memory");  // next tile landed
    cb ^= 1;
  }

  const float inv = 1.0f / l;
  unsigned int* op = (unsigned int*)(O + (size_t)(qw0 + ql) * 2048 + h * 64);
#pragma unroll
  for (int r = 0; r < 16; r += 2) {
    const int d = (r & 3) + ((r >> 2) << 3) + (hi << 2);
    op[d >> 1] = packbf(acc0[r] * inv, acc0[r + 1] * inv);
    op[(d >> 1) + 16] = packbf(acc1[r] * inv, acc1[r + 1] * inv);
  }
}

// ---------------- launcher ----------------
// Workspace (96 MB + 64 KB), offsets from `big` (MB):
//   0-16   w1z(i8) [->FFN gemm]  ... then fq(i8) after rowq32
//   16-32  w2z(i8)
//   32-36  wqz  36-37 wkz (contiguous [2560][2048])  37-38 wvz  38-42 woz
//   42-46  xq1(i8) [->proj gemms]   ... then oq(i8) after rowq8
//   46-66  accQK(i32) [->epiQK]     ... then accO(i32) [wo gemm->epi1ln]
//   66-70  accVt(i32) [->epiVt]
//   70-72  Kh  72-74 Vtb  74-82 Qb  [epis->attn]
//   82-90  Ob                       [attn->rowq8]
//   80-96  x1(f32)                  [epi1ln->end; Qb/Ob dead by then]
//   74-78  xq2(i8)  42-74 Fb(bf16)  [epi1ln->gemm2->rowq32]
//   42-58  accF(i32)                [w2 gemm->epi2]
extern "C" void kernel_launch(void* const* d_in, const int* in_sizes, int n_in, void* d_out,
                              int out_size, void* d_ws, size_t ws_size, hipStream_t stream) {
  const void* x = d_in[0];
  const void* g1 = d_in[1];
  const void* b1 = d_in[2];
  const void* g2 = d_in[3];
  const void* b2 = d_in[4];
  const void* wq = d_in[5];
  const void* wk = d_in[6];
  const void* wv = d_in[7];
  const void* wo = d_in[8];
  const void* w1 = d_in[9];
  const void* w2 = d_in[10];

  char* ws = (char*)d_ws;
  const size_t MB = 1ull << 20;
  float* wsum = (float*)ws;
  float* s1 = (float*)(ws + 8192);
  float* so = (float*)(ws + 16384);
  float* s2 = (float*)(ws + 24576);
  float* sf = (float*)(ws + 32768);
  int* flag = (int*)(ws + 40960);
  char* big = ws + 65536;

  i8* w1z = (i8*)(big);
  i8* fq  = (i8*)(big);
  i8* w2z = (i8*)(big + 16 * MB);
  i8* wqz = (i8*)(big + 32 * MB);   // [2560][2048] contiguous with wkz
  i8* wkz = (i8*)(big + 36 * MB);
  i8* wvz = (i8*)(big + 37 * MB);
  i8* woz = (i8*)(big + 38 * MB);
  i8* xq1 = (i8*)(big + 42 * MB);
  i8* oq  = xq1;
  int* accQK = (int*)(big + 46 * MB);   // [2048][2560]
  int* accVt = (int*)(big + 66 * MB);   // [512][2048]
  bf16* Kh   = (bf16*)(big + 70 * MB);  // [8][2048][64] swizzled tiles
  bf16* Vtb  = (bf16*)(big + 72 * MB);  // [8][64][64][32] swizzled tiles
  bf16* Qb   = (bf16*)(big + 74 * MB);
  bf16* Ob   = (bf16*)(big + 82 * MB);
  int* accO  = (int*)(big + 46 * MB);   // [2048][2048]
  float* x1  = (float*)(big + 80 * MB);
  i8* xq2 = (i8*)(big + 74 * MB);
  bf16* Fb   = (bf16*)(big + 42 * MB);  // [2048][8192]
  int* accF  = (int*)(big + 42 * MB);   // [2048][2048]

  k_sniff<<<1, 64, 0, stream>>>((const unsigned short*)x, flag);
  k_zero<<<1, 64, 0, stream>>>(wsum, 8);
  // zero accQK+accVt (contiguous 24MB @46-70)
  k_zerof<<<6144, 256, 0, stream>>>((float4*)accQK);

  k_abssum6<<<672, 256, 0, stream>>>(wq, wk, wv, wo, w1, w2, flag, wsum);
  k_wquant6<<<21504, 256, 0, stream>>>(wq, wk, wv, wo, w1, w2,
                                       wqz, wkz, wvz, woz, w1z, w2z, wsum, flag);

  // ---- attention sublayer ----
  k_lnq<false><<<2048, 256, 0, stream>>>(x, g1, b1, xq1, s1, flag);
  // fused Q+K projection: B = [wqz;wkz] (2560 rows), split-K x4 -> accQK
  k_gemm<4><<<dim3(20, 16, 4), 256, 0, stream>>>(xq1, wqz, s1, wsum + 0, INV_D2, accQK,
                                                 2048, 2560, 2048, 512, flag);
  // V^T directly: C[d][t] = wvz[d].xq1[t], split-K x4 -> accVt
  k_gemm<4><<<dim3(16, 4, 4), 256, 0, stream>>>(wvz, xq1, s1, wsum + 2, INV_KV, accVt,
                                                512, 2048, 2048, 512, flag);
  k_epiQK<<<2048, 256, 0, stream>>>(accQK, s1, wsum, Qb, Kh);
  k_epiVt<<<512, 256, 0, stream>>>(accVt, s1, wsum, Vtb);
  k_attn<<<dim3(64, 32), 64, 0, stream>>>(Qb, Kh, Vtb, Ob);
  k_rowq<8><<<2048, 256, 0, stream>>>(Ob, oq, so);
  k_zerof<<<4096, 256, 0, stream>>>((float4*)accO);  // after epiQK read accQK
  k_gemm<4><<<dim3(16, 16, 4), 256, 0, stream>>>(oq, woz, so, wsum + 3, INV_D2, accO,
                                                 2048, 2048, 2048, 512, flag);
  // fused: x1 = x + wo-out; LN(g2,b2); quant -> xq2,s2
  k_epi1ln<<<2048, 256, 0, stream>>>(accO, so, wsum, x, x1, g2, b2, xq2, s2, flag);

  // ---- FFN sublayer ----
  k_gemm<2><<<dim3(64, 16, 1), 256, 0, stream>>>(xq2, w1z, s2, wsum + 4, INV_F, Fb,
                                                 2048, 8192, 2048, 2048, flag);
  k_rowq<32><<<2048, 256, 0, stream>>>(Fb, fq, sf);  // fq overwrites dead w1z
  k_zerof<<<4096, 256, 0, stream>>>((float4*)accF);  // after rowq read Fb
  k_gemm<4><<<dim3(16, 16, 4), 256, 0, stream>>>(fq, w2z, sf, wsum + 5, INV_F, accF,
                                                 2048, 2048, 8192, 2048, flag);
  k_epi<2><<<2048, 256, 0, stream>>>(accF, 2048, 0, 2048, sf, wsum + 5, INV_F, x1, d_out, flag);
}

// Round 11
// 661.466 us; speedup vs baseline: 1.0034x; 1.0034x over previous
//
#include <hip/hip_runtime.h>
#include <hip/hip_bf16.h>
#include <stdint.h>

typedef __bf16 bf16;
typedef signed char i8;
typedef __bf16 v8bf __attribute__((ext_vector_type(8)));
typedef __bf16 v4bf __attribute__((ext_vector_type(4)));
typedef signed char v8i8 __attribute__((ext_vector_type(8)));
typedef int    v4i  __attribute__((ext_vector_type(4)));
typedef float  f32x16 __attribute__((ext_vector_type(16)));

#define MFMA32(a,b,c)   __builtin_amdgcn_mfma_f32_32x32x16_bf16((a),(b),(c),0,0,0)
#define MFMA_I8(a,b,c)  __builtin_amdgcn_mfma_i32_16x16x64_i8((a),(b),(c),0,0,0)

#define INV_D2 (1.0f / 4194304.0f)
#define INV_KV (1.0f / 1048576.0f)
#define INV_F  (1.0f / 16777216.0f)

__device__ __forceinline__ void glds16(const void* g, void* l) {
  __builtin_amdgcn_global_load_lds(
      (const __attribute__((address_space(1))) void*)g,
      (__attribute__((address_space(3))) void*)l, 16, 0, 0);
}

__device__ __forceinline__ float wred_sum(float v) {
#pragma unroll
  for (int o = 32; o; o >>= 1) v += __shfl_xor(v, o);
  return v;
}
__device__ __forceinline__ float wred_max(float v) {
#pragma unroll
  for (int o = 32; o; o >>= 1) v = fmaxf(v, __shfl_xor(v, o));
  return v;
}

__device__ __forceinline__ unsigned int packbf(float a, float b) {
  union { bf16 h[2]; unsigned int u; } x;
  x.h[0] = (bf16)a; x.h[1] = (bf16)b;
  return x.u;
}

// ---------------- dtype sniffer (inputs turned out fp32; keep robust) ----------------
__global__ void k_sniff(const unsigned short* __restrict__ x, int* __restrict__ flag) {
  int cnt = 0;
  for (int i = threadIdx.x; i < 2048; i += 64) {
    const unsigned short u = x[i];
    const int e = (u >> 7) & 0xFF;
    if (u == 0 || (e >= 100 && e <= 140)) cnt++;
  }
#pragma unroll
  for (int o = 32; o; o >>= 1) cnt += __shfl_xor(cnt, o);
  if (threadIdx.x == 0) flag[0] = (cnt >= 1844) ? 0 : 1;  // 0 = bf16, 1 = f32
}

// ---------------- small utility kernels ----------------

__global__ void k_zero(float* p, int n) {
  int i = threadIdx.x;
  if (i < n) p[i] = 0.0f;
}

// zero a float4-aligned buffer; grid = bytes/16/256
__global__ __launch_bounds__(256) void k_zerof(float4* __restrict__ p) {
  p[(size_t)blockIdx.x * 256 + threadIdx.x] = make_float4(0.f, 0.f, 0.f, 0.f);
}

// fused abs-sum over all 6 weights; segments in 64K-element units:
// wq 64 | wk 16 | wv 16 | wo 64 | w1 256 | w2 256  => grid = 672 blocks
__global__ __launch_bounds__(256) void k_abssum6(const void* __restrict__ p0, const void* __restrict__ p1,
                                                 const void* __restrict__ p2, const void* __restrict__ p3,
                                                 const void* __restrict__ p4, const void* __restrict__ p5,
                                                 const int* __restrict__ flag, float* __restrict__ out) {
  const int b = blockIdx.x, tid = threadIdx.x;
  const void* w; int seg, base;
  if (b < 64)       { w = p0; seg = 0; base = b; }
  else if (b < 80)  { w = p1; seg = 1; base = b - 64; }
  else if (b < 96)  { w = p2; seg = 2; base = b - 80; }
  else if (b < 160) { w = p3; seg = 3; base = b - 96; }
  else if (b < 416) { w = p4; seg = 4; base = b - 160; }
  else              { w = p5; seg = 5; base = b - 416; }
  const int f32 = flag[0];
  __shared__ float sred[4];
  float s = 0.0f;
  if (f32) {
    const float4* p = (const float4*)w + (size_t)base * 16384;
#pragma unroll 4
    for (int i = 0; i < 64; i++) {
      float4 a = p[i * 256 + tid];
      s += fabsf(a.x) + fabsf(a.y) + fabsf(a.z) + fabsf(a.w);
    }
  } else {
    const v8bf* p = (const v8bf*)w + (size_t)base * 8192;
#pragma unroll 4
    for (int i = 0; i < 32; i++) {
      v8bf v = p[i * 256 + tid];
#pragma unroll
      for (int j = 0; j < 8; j++) s += fabsf((float)v[j]);
    }
  }
  s = wred_sum(s);
  if ((tid & 63) == 0) sred[tid >> 6] = s;
  __syncthreads();
  if (tid == 0) atomicAdd(out + seg, sred[0] + sred[1] + sred[2] + sred[3]);
}

// fused ternary weight quant -> int8 for all 6 weights; 2048 elems/block:
// wq 2048 | wk 512 | wv 512 | wo 2048 | w1 8192 | w2 8192 => grid = 21504
__global__ __launch_bounds__(256) void k_wquant6(const void* __restrict__ p0, const void* __restrict__ p1,
                                                 const void* __restrict__ p2, const void* __restrict__ p3,
                                                 const void* __restrict__ p4, const void* __restrict__ p5,
                                                 i8* __restrict__ d0, i8* __restrict__ d1,
                                                 i8* __restrict__ d2, i8* __restrict__ d3,
                                                 i8* __restrict__ d4, i8* __restrict__ d5,
                                                 const float* __restrict__ wsum,
                                                 const int* __restrict__ flag) {
  const int b = blockIdx.x;
  const void* w; i8* o; int seg, base; float invn;
  if (b < 2048)       { w = p0; o = d0; seg = 0; base = b;         invn = INV_D2; }
  else if (b < 2560)  { w = p1; o = d1; seg = 1; base = b - 2048;  invn = INV_KV; }
  else if (b < 3072)  { w = p2; o = d2; seg = 2; base = b - 2560;  invn = INV_KV; }
  else if (b < 5120)  { w = p3; o = d3; seg = 3; base = b - 3072;  invn = INV_D2; }
  else if (b < 13312) { w = p4; o = d4; seg = 4; base = b - 5120;  invn = INV_F; }
  else                { w = p5; o = d5; seg = 5; base = b - 13312; invn = INV_F; }
  const int gid = base * 256 + threadIdx.x;
  const int i = gid * 8;
  const float ws = 1.0f / fmaxf(wsum[seg] * invn, 1e-5f);
  const int f32 = flag[0];
  float v[8];
  if (f32) {
    float4 a = ((const float4*)w)[gid * 2];
    float4 b4 = ((const float4*)w)[gid * 2 + 1];
    v[0] = a.x; v[1] = a.y; v[2] = a.z; v[3] = a.w;
    v[4] = b4.x; v[5] = b4.y; v[6] = b4.z; v[7] = b4.w;
  } else {
    v8bf t = *(const v8bf*)((const bf16*)w + i);
#pragma unroll
    for (int j = 0; j < 8; j++) v[j] = (float)t[j];
  }
  v8i8 r;
#pragma unroll
  for (int j = 0; j < 8; j++) {
    float t = rintf(v[j] * ws);
    r[j] = (i8)fminf(fmaxf(t, -1.0f), 1.0f);
  }
  *(v8i8*)(o + i) = r;
}

// LayerNorm + per-row absmax quantize -> int8.
template <bool XINT>
__global__ __launch_bounds__(256) void k_lnq(const void* __restrict__ x, const void* __restrict__ g,
                                             const void* __restrict__ b, i8* __restrict__ q,
                                             float* __restrict__ sc, const int* __restrict__ flag) {
  const int row = blockIdx.x, tid = threadIdx.x;
  const int f32 = flag[0];
  __shared__ float sred[4];
  float v[8];
#pragma unroll
  for (int i = 0; i < 8; i++) {
    const size_t idx = (size_t)row * 2048 + tid + 256 * i;
    if (XINT)      v[i] = ((const float*)x)[idx];
    else if (f32)  v[i] = ((const float*)x)[idx];
    else           v[i] = (float)((const bf16*)x)[idx];
  }
  float s = 0.0f;
#pragma unroll
  for (int i = 0; i < 8; i++) s += v[i];
  s = wred_sum(s);
  if ((tid & 63) == 0) sred[tid >> 6] = s;
  __syncthreads();
  const float mean = (sred[0] + sred[1] + sred[2] + sred[3]) * (1.0f / 2048.0f);
  __syncthreads();
  float vs = 0.0f;
#pragma unroll
  for (int i = 0; i < 8; i++) { float d = v[i] - mean; vs += d * d; }
  vs = wred_sum(vs);
  if ((tid & 63) == 0) sred[tid >> 6] = vs;
  __syncthreads();
  const float rstd = rsqrtf((sred[0] + sred[1] + sred[2] + sred[3]) * (1.0f / 2048.0f) + 1e-6f);
  __syncthreads();
  float hq[8];
  float am = 0.0f;
#pragma unroll
  for (int i = 0; i < 8; i++) {
    const int c = tid + 256 * i;
    const float gv = f32 ? ((const float*)g)[c] : (float)((const bf16*)g)[c];
    const float bv = f32 ? ((const float*)b)[c] : (float)((const bf16*)b)[c];
    hq[i] = (v[i] - mean) * rstd * gv + bv;
    am = fmaxf(am, fabsf(hq[i]));
  }
  am = wred_max(am);
  if ((tid & 63) == 0) sred[tid >> 6] = am;
  __syncthreads();
  am = fmaxf(fmaxf(sred[0], sred[1]), fmaxf(sred[2], sred[3]));
  const float cl = fmaxf(am, 1e-5f);
  const float s127 = 127.0f / cl;
#pragma unroll
  for (int i = 0; i < 8; i++) {
    float r = rintf(hq[i] * s127);
    r = fminf(fmaxf(r, -128.0f), 127.0f);
    q[(size_t)row * 2048 + tid + 256 * i] = (i8)r;
  }
  if (tid == 0) sc[row] = cl * (1.0f / 127.0f);
}

// plain per-row absmax quantize bf16 -> int8
template <int IT>
__global__ __launch_bounds__(256) void k_rowq(const bf16* __restrict__ in, i8* __restrict__ q,
                                              float* __restrict__ sc) {
  const int row = blockIdx.x, tid = threadIdx.x;
  const int C = IT * 256;
  __shared__ float sred[4];
  const bf16* xr = in + (size_t)row * C;
  float v[IT];
  float am = 0.0f;
#pragma unroll
  for (int i = 0; i < IT; i++) {
    v[i] = (float)xr[tid + 256 * i];
    am = fmaxf(am, fabsf(v[i]));
  }
  am = wred_max(am);
  if ((tid & 63) == 0) sred[tid >> 6] = am;
  __syncthreads();
  am = fmaxf(fmaxf(sred[0], sred[1]), fmaxf(sred[2], sred[3]));
  const float cl = fmaxf(am, 1e-5f);
  const float s127 = 127.0f / cl;
#pragma unroll
  for (int i = 0; i < IT; i++) {
    float r = rintf(v[i] * s127);
    r = fminf(fmaxf(r, -128.0f), 127.0f);
    q[(size_t)row * C + tid + 256 * i] = (i8)r;
  }
  if (tid == 0) sc[row] = cl * (1.0f / 127.0f);
}

// ---------------- int8 GEMM: counted-vmcnt pipeline + T2 LDS XOR-swizzle ----------------
// NEW (T2): the [128][64B] i8 tile had an 8-way bank conflict on ds_read_b128
// (row stride 64B = 2 bank-windows; SQ_LDS_BANK_CONFLICT=8.4M/dispatch). Fix per
// rule #21 (gload_lds writes linearly -> pre-swizzle the GLOBAL source):
//   write: lane l stages chunk c_log = (l&3) ^ ((l>>3)&3)  [permutes within 64B row]
//   read : fragment chunk = q4 ^ ((ml>>1)&3)
// -> physical chunk = logical ^ ((row>>1)&3) on both sides; readers of 16 rows
// spread across all 4 chunk-windows = 2 lanes/bank (free, m136).
// EPI 2: out bf16 = relu(sA[m]*cw*val)^2   (w1 -> F; direct, no split)
// EPI 4: atomicAdd i32 partial into out    (split-K; exact integer)
template <int EPI>
__global__ __launch_bounds__(256) void k_gemm(const i8* __restrict__ A, const i8* __restrict__ B,
                                              const float* __restrict__ sA,
                                              const float* __restrict__ wsum, float winv,
                                              void* __restrict__ out,
                                              int M, int N, int K, int Kc,
                                              const int* __restrict__ flag) {
  __shared__ __align__(16) i8 As[2][128 * 64];
  __shared__ __align__(16) i8 Bs[2][128 * 64];
  const int tid = threadIdx.x;
  const int lane = tid & 63;
  const int ml = lane & 15;
  const int q4 = lane >> 4;
  const int wid = tid >> 6;
  const int wM = wid >> 1;
  const int wN = wid & 1;
  const int m0 = blockIdx.y * 128;
  const int n0 = blockIdx.x * 128;

  const int r0 = tid >> 2;                                   // 0..63 (row)
  const int c0 = (((tid & 3) ^ ((tid >> 3) & 3)) * 16);      // pre-swizzled chunk
  const i8* Ag0 = A + (size_t)(m0 + r0) * K + c0;
  const i8* Ag1 = Ag0 + (size_t)64 * K;
  const i8* Bg0 = B + (size_t)(n0 + r0) * K + c0;
  const i8* Bg1 = Bg0 + (size_t)64 * K;
  const int l0 = wid * 1024;         // lane l of wave w -> wavebase + l*16B (linear dest)
  const int l1 = 4096 + wid * 1024;

  const int kbeg = blockIdx.z * Kc;
  const int nst = Kc >> 6;

  auto issue = [&](int tt) {
    const int k0 = kbeg + (tt << 6);
    const int bb = tt & 1;
    glds16(Ag0 + k0, &As[bb][l0]);
    glds16(Ag1 + k0, &As[bb][l1]);
    glds16(Bg0 + k0, &Bs[bb][l0]);
    glds16(Bg1 + k0, &Bs[bb][l1]);
  };

  // prologue: prime 2 tiles, wait tile 0 (tile 1 stays in flight)
  issue(0);
  if (nst > 1) {
    issue(1);
    asm volatile("s_waitcnt vmcnt(4)" ::: "memory");
  } else {
    asm volatile("s_waitcnt vmcnt(0)" ::: "memory");
  }
  __builtin_amdgcn_s_barrier();
  __builtin_amdgcn_sched_barrier(0);

  v4i acc[4][4] = {};
  const int sw = (ml >> 1) & 3;      // read-side swizzle (== (row>>1)&3 for all frag rows)

  for (int t = 0; t < nst; ++t) {
    const int cb = t & 1;
    v4i af[4], bfr[4];
#pragma unroll
    for (int i = 0; i < 4; i++)
      af[i] = *(const v4i*)&As[cb][(wM * 64 + i * 16 + ml) * 64 + ((q4 ^ sw) << 4)];
#pragma unroll
    for (int j = 0; j < 4; j++)
      bfr[j] = *(const v4i*)&Bs[cb][(wN * 64 + j * 16 + ml) * 64 + ((q4 ^ sw) << 4)];
#pragma unroll
    for (int i = 0; i < 4; i++)
#pragma unroll
      for (int j = 0; j < 4; j++) acc[i][j] = MFMA_I8(af[i], bfr[j], acc[i][j]);
    __builtin_amdgcn_sched_barrier(0);
    __builtin_amdgcn_s_barrier();          // all waves done reading buf[cb]
    __builtin_amdgcn_sched_barrier(0);
    if (t + 2 < nst) {
      issue(t + 2);                        // overwrite buf[cb]
      asm volatile("s_waitcnt vmcnt(4)" ::: "memory");  // tile t+1 landed; t+2 in flight
      __builtin_amdgcn_s_barrier();
      __builtin_amdgcn_sched_barrier(0);
    } else if (t + 1 < nst) {
      asm volatile("s_waitcnt vmcnt(0)" ::: "memory");  // only tile t+1 outstanding
      __builtin_amdgcn_s_barrier();
      __builtin_amdgcn_sched_barrier(0);
    }
  }

  if (EPI == 4) {
    int* ob = (int*)out;
#pragma unroll
    for (int i = 0; i < 4; i++)
#pragma unroll
      for (int r = 0; r < 4; r++) {
        const int row = m0 + wM * 64 + i * 16 + q4 * 4 + r;
#pragma unroll
        for (int j = 0; j < 4; j++) {
          const int col = n0 + wN * 64 + j * 16 + ml;
          atomicAdd(ob + (size_t)row * N + col, acc[i][j][r]);
        }
      }
    return;
  }

  // EPI == 2 (direct relu^2 bf16)
  const float cw = fmaxf(wsum[0] * winv, 1e-5f);
#pragma unroll
  for (int i = 0; i < 4; i++) {
#pragma unroll
    for (int r = 0; r < 4; r++) {
      const int row = m0 + wM * 64 + i * 16 + q4 * 4 + r;
      const float sa = sA[row] * cw;
#pragma unroll
      for (int j = 0; j < 4; j++) {
        const int col = n0 + wN * 64 + j * 16 + ml;
        const float val = (float)acc[i][j][r] * sa;
        float u = fmaxf(val, 0.0f);
        ((bf16*)out)[(size_t)row * N + col] = (bf16)(u * u);
      }
    }
  }
}

// ---------------- split-K scale/residual epilogues (i32 acc in) ----------------
// MODE 2: out flag-typed = x1(f32) + acc*sA[row]*cw     (final)
template <int MODE>
__global__ __launch_bounds__(256) void k_epi(const int* __restrict__ acc, int lda, int cofs,
                                             int ncols,
                                             const float* __restrict__ sA,
                                             const float* __restrict__ wsum, float winv,
                                             const void* __restrict__ resid,
                                             void* __restrict__ out,
                                             const int* __restrict__ flag) {
  const int row = blockIdx.x, tid = threadIdx.x;
  const float cw = fmaxf(wsum[0] * winv, 1e-5f);
  const float srow = sA[row] * cw;
  const int f32 = flag[0];
  for (int c = tid * 4; c < ncols; c += 1024) {
    const v4i a = *(const v4i*)(acc + (size_t)row * lda + cofs + c);
    const float v0 = (float)a[0] * srow, v1 = (float)a[1] * srow;
    const float v2 = (float)a[2] * srow, v3 = (float)a[3] * srow;
    const size_t o = (size_t)row * ncols + c;
    const float4 rv = *(const float4*)((const float*)resid + o);
    const float o0 = rv.x + v0, o1 = rv.y + v1, o2 = rv.z + v2, o3 = rv.w + v3;
    if (f32) {
      *(float4*)((float*)out + o) = make_float4(o0, o1, o2, o3);
    } else {
      v4bf r;
      r[0] = (bf16)o0; r[1] = (bf16)o1; r[2] = (bf16)o2; r[3] = (bf16)o3;
      *(v4bf*)((bf16*)out + o) = r;
    }
  }
}

// fused wo-epilogue + LayerNorm + quant: x1 = x + acc*so[row]*cw (write f32),
// then LN(g2,b2) + row absmax quant -> xq2, s2.
__global__ __launch_bounds__(256) void k_epi1ln(const int* __restrict__ acc,
                                                const float* __restrict__ so_,
                                                const float* __restrict__ wsum,
                                                const void* __restrict__ xres,
                                                float* __restrict__ x1,
                                                const void* __restrict__ g, const void* __restrict__ b,
                                                i8* __restrict__ q, float* __restrict__ sc,
                                                const int* __restrict__ flag) {
  const int row = blockIdx.x, tid = threadIdx.x;
  const int f32 = flag[0];
  __shared__ float sred[4];
  const float srow = so_[row] * fmaxf(wsum[3] * INV_D2, 1e-5f);
  float v[8];
#pragma unroll
  for (int i = 0; i < 8; i++) {
    const size_t idx = (size_t)row * 2048 + tid + 256 * i;
    const float a = (float)acc[idx] * srow;
    const float rv = f32 ? ((const float*)xres)[idx] : (float)((const bf16*)xres)[idx];
    v[i] = rv + a;
    x1[idx] = v[i];
  }
  float s = 0.0f;
#pragma unroll
  for (int i = 0; i < 8; i++) s += v[i];
  s = wred_sum(s);
  if ((tid & 63) == 0) sred[tid >> 6] = s;
  __syncthreads();
  const float mean = (sred[0] + sred[1] + sred[2] + sred[3]) * (1.0f / 2048.0f);
  __syncthreads();
  float vs = 0.0f;
#pragma unroll
  for (int i = 0; i < 8; i++) { float d = v[i] - mean; vs += d * d; }
  vs = wred_sum(vs);
  if ((tid & 63) == 0) sred[tid >> 6] = vs;
  __syncthreads();
  const float rstd = rsqrtf((sred[0] + sred[1] + sred[2] + sred[3]) * (1.0f / 2048.0f) + 1e-6f);
  __syncthreads();
  float hq[8];
  float am = 0.0f;
#pragma unroll
  for (int i = 0; i < 8; i++) {
    const int c = tid + 256 * i;
    const float gv = f32 ? ((const float*)g)[c] : (float)((const bf16*)g)[c];
    const float bv = f32 ? ((const float*)b)[c] : (float)((const bf16*)b)[c];
    hq[i] = (v[i] - mean) * rstd * gv + bv;
    am = fmaxf(am, fabsf(hq[i]));
  }
  am = wred_max(am);
  if ((tid & 63) == 0) sred[tid >> 6] = am;
  __syncthreads();
  am = fmaxf(fmaxf(sred[0], sred[1]), fmaxf(sred[2], sred[3]));
  const float cl = fmaxf(am, 1e-5f);
  const float s127 = 127.0f / cl;
#pragma unroll
  for (int i = 0; i < 8; i++) {
    float r = rintf(hq[i] * s127);
    r = fminf(fmaxf(r, -128.0f), 127.0f);
    q[(size_t)row * 2048 + tid + 256 * i] = (i8)r;
  }
  if (tid == 0) sc[row] = cl * (1.0f / 127.0f);
}

// fused Q+K epilogue. Q: plain [t][2048]. K: head-major tiled PRE-SWIZZLED layout
// Kh[kvh][t][64]: elem = kvh*131072 + (t>>5)*2048 + (t&31)*64 + (((d>>3)^(t&7))<<3) + (d&7)
__global__ __launch_bounds__(256) void k_epiQK(const int* __restrict__ acc,
                                               const float* __restrict__ sA,
                                               const float* __restrict__ wsum,
                                               bf16* __restrict__ Qb, bf16* __restrict__ Kh) {
  const int row = blockIdx.x, tid = threadIdx.x;  // row = token t
  const float cw0 = fmaxf(wsum[0] * INV_D2, 1e-5f);
  const float cw1 = fmaxf(wsum[1] * INV_KV, 1e-5f);
  const float sa = sA[row];
  bf16* kb_ = Kh + ((size_t)(row >> 5) * 2048) + (row & 31) * 64;
  const int rx = row & 7;
  for (int c = tid * 4; c < 2560; c += 1024) {
    const v4i a = *(const v4i*)(acc + (size_t)row * 2560 + c);
    if (c < 2048) {
      v4bf r;
#pragma unroll
      for (int j = 0; j < 4; j++) r[j] = (bf16)((float)a[j] * sa * cw0);
      *(v4bf*)(Qb + (size_t)row * 2048 + c) = r;
    } else {
      const int j0 = c - 2048;
      const int kvh = j0 >> 6, d = j0 & 63;
      v4bf r;
#pragma unroll
      for (int j = 0; j < 4; j++) r[j] = (bf16)((float)a[j] * sa * cw1);
      const int elem = ((((d >> 3) ^ rx) << 3) + (d & 7));
      *(v4bf*)(kb_ + (size_t)kvh * 131072 + elem) = r;
    }
  }
}

// Vt epilogue -> head-major tile-blocked PRE-SWIZZLED V^T:
// Vtb[kvh][tile][64 d][32 t]: elem = kvh*131072 + (t>>5)*2048 + d*32
//                                   + (((t&31)>>3 ^ ((d>>1)&3))<<3) + (t&7)
__global__ __launch_bounds__(256) void k_epiVt(const int* __restrict__ acc,
                                               const float* __restrict__ sT,
                                               const float* __restrict__ wsum,
                                               bf16* __restrict__ Vtb) {
  const int vr = blockIdx.x, tid = threadIdx.x;  // vr = 0..511 (kvh*64 + d)
  const int kvh = vr >> 6, dd = vr & 63;
  const float cw = fmaxf(wsum[2] * INV_KV, 1e-5f);
  const int sw = (dd >> 1) & 3;
  bf16* vb = Vtb + (size_t)kvh * 131072 + dd * 32;
  for (int c = tid * 4; c < 2048; c += 1024) {
    const v4i a = *(const v4i*)(acc + (size_t)vr * 2048 + c);
    const float4 sc = *(const float4*)(sT + c);
    v4bf r;
    r[0] = (bf16)((float)a[0] * sc.x * cw);
    r[1] = (bf16)((float)a[1] * sc.y * cw);
    r[2] = (bf16)((float)a[2] * sc.z * cw);
    r[3] = (bf16)((float)a[3] * sc.w * cw);
    const int tq = c & 31;
    const int elem = (c >> 5) * 2048 + ((((tq >> 3) ^ sw) << 3) + (tq & 7));
    *(v4bf*)(vb + elem) = r;
  }
}

// ---------------- MFMA flash attention (causal, GQA 32q/8kv heads, D=64) ----------------
// r8 form (90.5us): swapped-operand 32x32, in-register softmax, coalesced LDS
// staging from pre-swizzled head-major K/V, double-buffered. Parked at plateau.
__global__ __launch_bounds__(64) void k_attn(const bf16* __restrict__ Q, const bf16* __restrict__ Kh,
                                             const bf16* __restrict__ Vtb, bf16* __restrict__ O) {
  __shared__ __align__(16) bf16 Kl[2][2048];
  __shared__ __align__(16) bf16 Vl[2][2048];
  const int h = blockIdx.y;
  const int kvh = h >> 2;
  const int t = (blockIdx.x + ((h >> 2) << 3)) & 63;  // balanced q-tile swizzle
  const int qw0 = t * 32;
  const int lane = threadIdx.x;
  const int ql = lane & 31;
  const int hi = lane >> 5;

  v8bf qf[4];
  {
    const bf16* qp = Q + (size_t)(qw0 + ql) * 2048 + h * 64 + hi * 8;
#pragma unroll
    for (int c = 0; c < 4; c++) qf[c] = *(const v8bf*)(qp + c * 16);
  }

  float m = -1e30f, l = 0.0f;
  f32x16 acc0 = {}, acc1 = {};

  const bf16* khead = Kh + (size_t)kvh * 131072 + lane * 8;
  const bf16* vhead = Vtb + (size_t)kvh * 131072 + lane * 8;

#pragma unroll
  for (int cc = 0; cc < 4; cc++) {
    glds16(khead + cc * 512, &Kl[0][cc * 512]);
    glds16(vhead + cc * 512, &Vl[0][cc * 512]);
  }
  asm volatile("s_waitcnt vmcnt(0)" ::: "memory");
  int cb = 0;

  for (int kb = 0; kb <= qw0; kb += 32) {
    if (kb + 32 <= qw0) {
      const int tb = ((kb + 32) >> 5) * 2048;
#pragma unroll
      for (int cc = 0; cc < 4; cc++) {
        glds16(khead + tb + cc * 512, &Kl[cb ^ 1][cc * 512]);
        glds16(vhead + tb + cc * 512, &Vl[cb ^ 1][cc * 512]);
      }
    }
    f32x16 s = {};
    {
      const char* kl = (const char*)&Kl[cb][0] + ql * 128;
#pragma unroll
      for (int c = 0; c < 4; c++) {
        const int sl = ((2 * c + hi) ^ (ql & 7)) << 4;
        const v8bf kf = *(const v8bf*)(kl + sl);
        s = MFMA32(kf, qf[c], s);
      }
    }
    const bool diag = (kb == qw0);
    float p[16];
    float rm = -1e30f;
#pragma unroll
    for (int r = 0; r < 16; r++) {
      float v = s[r] * 0.125f;
      const int koff = (r & 3) + ((r >> 2) << 3) + (hi << 2);
      if (diag && koff > ql) v = -1e30f;
      p[r] = v;
      rm = fmaxf(rm, v);
    }
    rm = fmaxf(rm, __shfl_xor(rm, 32));
    const float mn = fmaxf(m, rm);
    const float alpha = __expf(m - mn);
    m = mn;
    float rs = 0.0f;
#pragma unroll
    for (int r = 0; r < 16; r++) {
      p[r] = __expf(p[r] - mn);
      rs += p[r];
    }
    rs += __shfl_xor(rs, 32);
    l = l * alpha + rs;
#pragma unroll
    for (int r = 0; r < 16; r++) { acc0[r] *= alpha; acc1[r] *= alpha; }

    unsigned int w0 = packbf(p[0], p[1]),   w2 = packbf(p[4], p[5]);
    unsigned int w1 = packbf(p[2], p[3]),   w3 = packbf(p[6], p[7]);
    unsigned int x0 = packbf(p[8], p[9]),   x2 = packbf(p[12], p[13]);
    unsigned int x1 = packbf(p[10], p[11]), x3 = packbf(p[14], p[15]);
    asm("v_permlane32_swap_b32 %0, %1" : "+v"(w0), "+v"(w2));
    asm("v_permlane32_swap_b32 %0, %1" : "+v"(w1), "+v"(w3));
    asm("v_permlane32_swap_b32 %0, %1" : "+v"(x0), "+v"(x2));
    asm("v_permlane32_swap_b32 %0, %1" : "+v"(x1), "+v"(x3));
    union BU { unsigned int u[4]; v8bf v; } B0, B1;
    B0.u[0] = w0; B0.u[1] = w1; B0.u[2] = w2; B0.u[3] = w3;
    B1.u[0] = x0; B1.u[1] = x1; B1.u[2] = x2; B1.u[3] = x3;

    {
      const char* vl = (const char*)&Vl[cb][0] + ql * 64;
      const int sx = (ql >> 1) & 3;
      const int sl0 = ((0 + hi) ^ sx) << 4;
      const int sl1 = ((2 + hi) ^ sx) << 4;
      const v8bf v00 = *(const v8bf*)(vl + sl0);
      const v8bf v01 = *(const v8bf*)(vl + sl1);
      const v8bf v10 = *(const v8bf*)(vl + 2048 + sl0);
      const v8bf v11 = *(const v8bf*)(vl + 2048 + sl1);
      acc0 = MFMA32(v00, B0.v, acc0);
      acc0 = MFMA32(v01, B1.v, acc0);
      acc1 = MFMA32(v10, B0.v, acc1);
      acc1 = MFMA32(v11, B1.v, acc1);
    }
    asm volatile("s_waitcnt vmcnt(0)" ::: "memory");  // next tile landed
    cb ^= 1;
  }

  const float inv = 1.0f / l;
  unsigned int* op = (unsigned int*)(O + (size_t)(qw0 + ql) * 2048 + h * 64);
#pragma unroll
  for (int r = 0; r < 16; r += 2) {
    const int d = (r & 3) + ((r >> 2) << 3) + (hi << 2);
    op[d >> 1] = packbf(acc0[r] * inv, acc0[r + 1] * inv);
    op[(d >> 1) + 16] = packbf(acc1[r] * inv, acc1[r + 1] * inv);
  }
}

// ---------------- launcher ----------------
// Workspace (96 MB + 64 KB), offsets from `big` (MB):
//   0-16   w1z(i8) [->FFN gemm]  ... then fq(i8) after rowq32
//   16-32  w2z(i8)
//   32-36  wqz  36-37 wkz (contiguous [2560][2048])  37-38 wvz  38-42 woz
//   42-46  xq1(i8) [->proj gemms]   ... then oq(i8) after rowq8
//   46-66  accQK(i32) [->epiQK]     ... then accO(i32) [wo gemm->epi1ln]
//   66-70  accVt(i32) [->epiVt]
//   70-72  Kh  72-74 Vtb  74-82 Qb  [epis->attn]
//   82-90  Ob                       [attn->rowq8]
//   80-96  x1(f32)                  [epi1ln->end; Qb/Ob dead by then]
//   74-78  xq2(i8)  42-74 Fb(bf16)  [epi1ln->gemm2->rowq32]
//   42-58  accF(i32)                [w2 gemm->epi2]
extern "C" void kernel_launch(void* const* d_in, const int* in_sizes, int n_in, void* d_out,
                              int out_size, void* d_ws, size_t ws_size, hipStream_t stream) {
  const void* x = d_in[0];
  const void* g1 = d_in[1];
  const void* b1 = d_in[2];
  const void* g2 = d_in[3];
  const void* b2 = d_in[4];
  const void* wq = d_in[5];
  const void* wk = d_in[6];
  const void* wv = d_in[7];
  const void* wo = d_in[8];
  const void* w1 = d_in[9];
  const void* w2 = d_in[10];

  char* ws = (char*)d_ws;
  const size_t MB = 1ull << 20;
  float* wsum = (float*)ws;
  float* s1 = (float*)(ws + 8192);
  float* so = (float*)(ws + 16384);
  float* s2 = (float*)(ws + 24576);
  float* sf = (float*)(ws + 32768);
  int* flag = (int*)(ws + 40960);
  char* big = ws + 65536;

  i8* w1z = (i8*)(big);
  i8* fq  = (i8*)(big);
  i8* w2z = (i8*)(big + 16 * MB);
  i8* wqz = (i8*)(big + 32 * MB);   // [2560][2048] contiguous with wkz
  i8* wkz = (i8*)(big + 36 * MB);
  i8* wvz = (i8*)(big + 37 * MB);
  i8* woz = (i8*)(big + 38 * MB);
  i8* xq1 = (i8*)(big + 42 * MB);
  i8* oq  = xq1;
  int* accQK = (int*)(big + 46 * MB);   // [2048][2560]
  int* accVt = (int*)(big + 66 * MB);   // [512][2048]
  bf16* Kh   = (bf16*)(big + 70 * MB);  // [8][2048][64] swizzled tiles
  bf16* Vtb  = (bf16*)(big + 72 * MB);  // [8][64][64][32] swizzled tiles
  bf16* Qb   = (bf16*)(big + 74 * MB);
  bf16* Ob   = (bf16*)(big + 82 * MB);
  int* accO  = (int*)(big + 46 * MB);   // [2048][2048]
  float* x1  = (float*)(big + 80 * MB);
  i8* xq2 = (i8*)(big + 74 * MB);
  bf16* Fb   = (bf16*)(big + 42 * MB);  // [2048][8192]
  int* accF  = (int*)(big + 42 * MB);   // [2048][2048]

  k_sniff<<<1, 64, 0, stream>>>((const unsigned short*)x, flag);
  k_zero<<<1, 64, 0, stream>>>(wsum, 8);
  // zero accQK+accVt (contiguous 24MB @46-70)
  k_zerof<<<6144, 256, 0, stream>>>((float4*)accQK);

  k_abssum6<<<672, 256, 0, stream>>>(wq, wk, wv, wo, w1, w2, flag, wsum);
  k_wquant6<<<21504, 256, 0, stream>>>(wq, wk, wv, wo, w1, w2,
                                       wqz, wkz, wvz, woz, w1z, w2z, wsum, flag);

  // ---- attention sublayer ----
  k_lnq<false><<<2048, 256, 0, stream>>>(x, g1, b1, xq1, s1, flag);
  // fused Q+K projection: B = [wqz;wkz] (2560 rows), split-K x4 -> accQK
  k_gemm<4><<<dim3(20, 16, 4), 256, 0, stream>>>(xq1, wqz, s1, wsum + 0, INV_D2, accQK,
                                                 2048, 2560, 2048, 512, flag);
  // V^T directly: C[d][t] = wvz[d].xq1[t], split-K x4 -> accVt
  k_gemm<4><<<dim3(16, 4, 4), 256, 0, stream>>>(wvz, xq1, s1, wsum + 2, INV_KV, accVt,
                                                512, 2048, 2048, 512, flag);
  k_epiQK<<<2048, 256, 0, stream>>>(accQK, s1, wsum, Qb, Kh);
  k_epiVt<<<512, 256, 0, stream>>>(accVt, s1, wsum, Vtb);
  k_attn<<<dim3(64, 32), 64, 0, stream>>>(Qb, Kh, Vtb, Ob);
  k_rowq<8><<<2048, 256, 0, stream>>>(Ob, oq, so);
  k_zerof<<<4096, 256, 0, stream>>>((float4*)accO);  // after epiQK read accQK
  k_gemm<4><<<dim3(16, 16, 4), 256, 0, stream>>>(oq, woz, so, wsum + 3, INV_D2, accO,
                                                 2048, 2048, 2048, 512, flag);
  // fused: x1 = x + wo-out; LN(g2,b2); quant -> xq2,s2
  k_epi1ln<<<2048, 256, 0, stream>>>(accO, so, wsum, x, x1, g2, b2, xq2, s2, flag);

  // ---- FFN sublayer ----
  k_gemm<2><<<dim3(64, 16, 1), 256, 0, stream>>>(xq2, w1z, s2, wsum + 4, INV_F, Fb,
                                                 2048, 8192, 2048, 2048, flag);
  k_rowq<32><<<2048, 256, 0, stream>>>(Fb, fq, sf);  // fq overwrites dead w1z
  k_zerof<<<4096, 256, 0, stream>>>((float4*)accF);  // after rowq read Fb
  k_gemm<4><<<dim3(16, 16, 4), 256, 0, stream>>>(fq, w2z, sf, wsum + 5, INV_F, accF,
                                                 2048, 2048, 8192, 2048, flag);
  k_epi<2><<<2048, 256, 0, stream>>>(accF, 2048, 0, 2048, sf, wsum + 5, INV_F, x1, d_out, flag);
}